// Round 8
// baseline (692.416 us; speedup 1.0000x reference)
//
#include <hip/hip_runtime.h>

#define BATCH 32
#define TIME  512
#define INF   512
#define HIDF  1024

#define MBT  128          // block tile: bt rows
#define NBH  128          // block tile: h cols
#define KCH  16           // k per chunk
#define NCH  (INF / KCH)  // 32 chunks
#define TILEF (MBT * KCH) // 2048 floats = 8 KB per x buffer

// async global->LDS DMA, 16 B per lane, dst = wave-uniform base + lane*16
#define GLD16(g, l) __builtin_amdgcn_global_load_lds(                      \
    (const __attribute__((address_space(1))) void*)(g),                    \
    (__attribute__((address_space(3))) void*)(l), 16, 0, 0)

// ---------------------------------------------------------------------------
// Phase 1: hidden[bt][h] = (sum_k x[bt,k]*W[h,k]) + bias[h], bit-exact vs the
// XLA canonical order: ONE fp32 accumulator per output, fused FMA, k strictly
// ascending, ONE fp32 rounding for +bias.
//
// R15: R13 (barriers null) + R14 (occupancy hurt) => a saturated shared
// pipe. At the observed 576k cyc for 32768 broadcast-b128/CU the LDS pipe
// is ~100% busy (~17.6 cyc per 8-way-broadcast b128); VALU 66%. The only
// way to cut LDS instr count at fixed tile (register cliff forbids bigger
// tiles - R9/R10/R12) is to move an operand OFF the LDS pipe: wf fragments
// now read DIRECTLY from global. W is 2 MB (L2-resident); per block-column
// the chunk working set is 8 KB (L1-warm). The vmem/TA pipe was idle.
// LDS demand halves to 16384 instr/CU; identical W bits, identical FMA
// order -> bit-exact. 4 base pointers (c=0,2,4,6), odd rows via immediate
// offset 2048+k*4 <= 4080: all 8 wf loads use imm offsets.
//
// Conflict-free x LDS scheme (R11, verified 0 conflicts): within each
// 16-row window, global row 8*(s&1)+(s>>1) is staged into slot s (pure
// permutation of the per-lane GLOBAL source address of GLD16; LDS dst
// linear), plus quad-XOR by (window&3). Octet ly reads slots (ly&1)+2r of
// window (ly>>1): bank group (ly&1)*16 + (g^(ly>>1))*4 -> 8 distinct
// quads, all 32 banks exactly once.
// Allocator facts: (256,2)->no clamp/no spill; waves_per_eu(2,2)->128+spill;
// (256,4)->64+spill; (256,3)->84, slower (R14). Stay at (256,2).
// ---------------------------------------------------------------------------

#define LDW(dst, koff)                                                     \
    dst[0] = *(const float4*)(pw0 + (koff));                               \
    dst[1] = *(const float4*)(pw0 + 512 + (koff));                         \
    dst[2] = *(const float4*)(pw1 + (koff));                               \
    dst[3] = *(const float4*)(pw1 + 512 + (koff));                         \
    dst[4] = *(const float4*)(pw2 + (koff));                               \
    dst[5] = *(const float4*)(pw2 + 512 + (koff));                         \
    dst[6] = *(const float4*)(pw3 + (koff));                               \
    dst[7] = *(const float4*)(pw3 + 512 + (koff));

#define LDX(dst, g)                                                        \
    {                                                                      \
        const float* xr_ = xb + xrow0 * KCH + ((g) ^ xq) * 4;              \
        _Pragma("unroll")                                                  \
        for (int r_ = 0; r_ < 8; ++r_)                                     \
            dst[r_] = *(const float4*)(xr_ + r_ * 2 * KCH);                \
    }

#define FMA_COMP(xf, wf, COMP)                                             \
    _Pragma("unroll")                                                      \
    for (int r_ = 0; r_ < 8; ++r_)                                         \
        _Pragma("unroll")                                                  \
        for (int c_ = 0; c_ < 8; ++c_)                                     \
            acc[r_][c_] = __fmaf_rn(xf[r_].COMP, wf[c_].COMP, acc[r_][c_]);

#define FMA_GROUP(xf, wf)                                                  \
    FMA_COMP(xf, wf, x)                                                    \
    FMA_COMP(xf, wf, y)                                                    \
    FMA_COMP(xf, wf, z)                                                    \
    FMA_COMP(xf, wf, w)

__global__ __launch_bounds__(256, 2)
void snn_gemm_seqfma(const float* __restrict__ x, const float* __restrict__ W,
                     const float* __restrict__ bias, float* __restrict__ hidden) {
    __shared__ __align__(16) float xs[2 * TILEF];   // 16 KB (x only)

    const int tid = threadIdx.x;
    const int l   = tid & 63;
    const int wv  = __builtin_amdgcn_readfirstlane(tid >> 6);  // wave 0..3
    const int lx  = l & 7;           // h octet within wave sub-tile
    const int ly  = (l >> 3) & 7;    // bt octet within wave sub-tile
    const int bt0 = blockIdx.y * MBT;
    const int h0  = blockIdx.x * NBH;
    // wave sub-tile origin inside the 128x128 block tile
    const int wbt = 64 * (wv >> 1);  // bt offset: 0 or 64
    const int wh  = 64 * (wv & 1);   // h  offset: 0 or 64

    // ---- x DMA staging: wave wv stages windows 2wv, 2wv+1 (16 rows) ----
    const int rl = l >> 2;                        // slot within window, 0..15
    const int qs = l & 3;                         // quad position, 0..3
    const int g0 = ((rl & 1) << 3) | (rl >> 1);   // global row offset for slot
    const int wA = 2 * wv;
    const int wB = 2 * wv + 1;
    const int rA = wA * 16 + g0;
    const int rB = wB * 16 + g0;
    const int qA = qs ^ (wA & 3);
    const int qB = qs ^ (wB & 3);
    const float* xgA = x + (size_t)(bt0 + rA) * INF + qA * 4;
    const float* xgB = x + (size_t)(bt0 + rB) * INF + qB * 4;
    const int dOffA = (32 * wv) * KCH;        // wave-uniform LDS float offset
    const int dOffB = dOffA + 16 * KCH;

    // ---- W global fragment bases: rows h0+wh+lx*8+c, c in {0,2,4,6};
    //      odd c via +512 floats (imm 2048 B), k via imm koff*4 B ----
    const float* pw0 = W + (size_t)(h0 + wh + lx * 8 + 0) * INF;
    const float* pw1 = W + (size_t)(h0 + wh + lx * 8 + 2) * INF;
    const float* pw2 = W + (size_t)(h0 + wh + lx * 8 + 4) * INF;
    const float* pw3 = W + (size_t)(h0 + wh + lx * 8 + 6) * INF;

    // ---- prologue: stage x chunk 0 into buffer 0 ----
    GLD16(xgA, xs + dOffA);
    GLD16(xgB, xs + dOffB);

    float acc[8][8];
    #pragma unroll
    for (int r = 0; r < 8; ++r)
        #pragma unroll
        for (int c = 0; c < 8; ++c) acc[r][c] = 0.0f;

    __syncthreads();   // drains vmcnt -> x chunk 0 resident

    // per-lane x read bases: octet o reads slots (o&1)+2r of window (o>>1)
    const int xrow0 = wbt + (ly >> 1) * 16 + (ly & 1);
    const int xq = (ly >> 1) & 3;    // quad-XOR seen by this lane's x rows

    for (int kc = 0; kc < NCH; ++kc) {
        const int p  = kc & 1;
        const int np = p ^ 1;
        const int k0 = kc * KCH;          // float offset within a row

        // ---- issue next x chunk's DMAs into the other buffer (async) ----
        if (kc + 1 < NCH) {
            const int so = k0 + KCH;
            float* xd = xs + np * TILEF;
            GLD16(xgA + so, xd + dOffA);
            GLD16(xgB + so, xd + dOffB);
        }

        // ---- compute: 4 groups of 4 k, g ascending; wf double-set
        //      pipelines global W loads one group ahead ----
        const float* xb = xs + p * TILEF;
        float4 xf[8], wfA[8], wfB[8];
        LDW(wfA, k0 + 0 * 4)
        LDX(xf, 0)
        LDW(wfB, k0 + 1 * 4)
        FMA_GROUP(xf, wfA)            // g = 0
        LDX(xf, 1)
        LDW(wfA, k0 + 2 * 4)
        FMA_GROUP(xf, wfB)            // g = 1
        LDX(xf, 2)
        LDW(wfB, k0 + 3 * 4)
        FMA_GROUP(xf, wfA)            // g = 2
        LDX(xf, 3)
        FMA_GROUP(xf, wfB)            // g = 3

        __syncthreads();   // all waves done with x buf p; np's DMAs drained
    }

    // ---- epilogue: one fp32 rounding for bias, float4 stores ----
    float bv[8];
    #pragma unroll
    for (int c = 0; c < 8; ++c) bv[c] = bias[h0 + wh + lx * 8 + c];
    #pragma unroll
    for (int r = 0; r < 8; ++r) {
        float* orow = hidden + (size_t)(bt0 + wbt + ly * 8 + r) * HIDF
                             + h0 + wh + lx * 8;
        float4 o0, o1;
        o0.x = __fadd_rn(acc[r][0], bv[0]);
        o0.y = __fadd_rn(acc[r][1], bv[1]);
        o0.z = __fadd_rn(acc[r][2], bv[2]);
        o0.w = __fadd_rn(acc[r][3], bv[3]);
        o1.x = __fadd_rn(acc[r][4], bv[4]);
        o1.y = __fadd_rn(acc[r][5], bv[5]);
        o1.z = __fadd_rn(acc[r][6], bv[6]);
        o1.w = __fadd_rn(acc[r][7], bv[7]);
        ((float4*)orow)[0] = o0;
        ((float4*)orow)[1] = o1;
    }
}

// ---------------------------------------------------------------------------
// Phase 2: in-place LIF scan over t per (b,h) column, fp32:
//   mem = fl32(0.5*mem + h_t); spk = mem > 1.0f; hard reset to 0.
// Residual (total - gemm) is harness overhead + ~15-20 us scan; left as-is.
// ---------------------------------------------------------------------------
#define SEG 32

__global__ __launch_bounds__(64)
void snn_scan_np(float* __restrict__ io) {
    const int n = blockIdx.x * 64 + threadIdx.x;   // 0..32767
    const int b = n >> 10;
    const int h = n & 1023;
    float* p = io + (size_t)b * TIME * HIDF + h;

    float A[SEG], B[SEG];
    float mem = 0.0f;

    #pragma unroll
    for (int u = 0; u < SEG; ++u) A[u] = p[u * HIDF];

    for (int tb = 0; tb < TIME / SEG; tb += 2) {
        #pragma unroll
        for (int u = 0; u < SEG; ++u) B[u] = p[((tb + 1) * SEG + u) * HIDF];
        #pragma unroll
        for (int u = 0; u < SEG; ++u) {
            mem = __fadd_rn(__fmul_rn(0.5f, mem), A[u]);
            const bool s = mem > 1.0f;
            p[(tb * SEG + u) * HIDF] = s ? 1.0f : 0.0f;
            if (s) mem = 0.0f;
        }
        if (tb + 2 < TIME / SEG) {
            #pragma unroll
            for (int u = 0; u < SEG; ++u) A[u] = p[((tb + 2) * SEG + u) * HIDF];
        }
        #pragma unroll
        for (int u = 0; u < SEG; ++u) {
            mem = __fadd_rn(__fmul_rn(0.5f, mem), B[u]);
            const bool s = mem > 1.0f;
            p[((tb + 1) * SEG + u) * HIDF] = s ? 1.0f : 0.0f;
            if (s) mem = 0.0f;
        }
    }
}

extern "C" void kernel_launch(void* const* d_in, const int* in_sizes, int n_in,
                              void* d_out, int out_size, void* d_ws, size_t ws_size,
                              hipStream_t stream) {
    const float* x    = (const float*)d_in[0];   // [32, 512, 512]
    const float* W    = (const float*)d_in[1];   // [1024, 512]
    const float* bias = (const float*)d_in[2];   // [1024]
    float* out = (float*)d_out;                  // [32, 512, 1024]

    dim3 g1(HIDF / NBH, (BATCH * TIME) / MBT);   // (8, 128) = 1024 blocks
    snn_gemm_seqfma<<<g1, 256, 0, stream>>>(x, W, bias, out);

    snn_scan_np<<<(BATCH * HIDF) / 64, 64, 0, stream>>>(out);
}

// Round 9
// 327.219 us; speedup vs baseline: 2.1161x; 2.1161x over previous
//
#include <hip/hip_runtime.h>

#define BATCH 32
#define TIME  512
#define INF   512
#define HIDF  1024

#define MBT  128          // block tile: bt rows
#define NBH  128          // block tile: h cols
#define KCH  16           // k per chunk
#define NCH  (INF / KCH)  // 32 chunks
#define TILEF (MBT * KCH) // 2048 floats = 8 KB per buffer

// async global->LDS DMA, 16 B per lane, dst = wave-uniform base + lane*16
#define GLD16(g, l) __builtin_amdgcn_global_load_lds(                      \
    (const __attribute__((address_space(1))) void*)(g),                    \
    (__attribute__((address_space(3))) void*)(l), 16, 0, 0)

// ---------------------------------------------------------------------------
// Phase 1: hidden[bt][h] = (sum_k x[bt,k]*W[h,k]) + bias[h], bit-exact vs the
// XLA canonical order: ONE fp32 accumulator per output, fused FMA, k strictly
// ascending, ONE fp32 rounding for +bias.
//
// R16 = R11 (best, 240.5 us) + issue-order fix. Evidence trail:
//  - R13: barrier-free == barriered (242 vs 240)  -> sync is not the wall
//  - R14: 3 waves/SIMD -> worse (257)             -> TLP is not the fix
//  - R15: W-from-global -> 646 us                 -> vmem latency kills it
//  - R8:  source-level double-set -> compiler re-coalesced (VGPR 88)
// Remaining measured bubble: 34% VALU idle from the [16 ds_read][wait]
// [256 FMA] per-group emission - the ds latency head of each group is
// exposed. Fix: two fragment sets + sched_group_barrier (T19) pinning the
// issue order per group to 8x{2 DS_READ, 16 VALU} + 128-VALU tail, so
// group g+1's reads issue under group g's FMAs and the last read has
// ~256 FMA-cycles of cover. Compile-time directive - the allocator cannot
// coalesce it away like R8. FMA order per accumulator unchanged.
//
// Conflict-free LDS scheme (R11, verified 0 conflicts): within each 16-row
// window, global row 8*(s&1)+(s>>1) is staged into slot s (pure GLOBAL-
// source permutation of GLD16; LDS dst linear), plus quad-XOR by (window&3).
// Octet ly reads slots (ly&1)+2r of window (ly>>1): bank group
// (ly&1)*16 + (g^(ly>>1))*4 -> 8 distinct quads, all 32 banks exactly once.
// Allocator bracket: (256,2)->no clamp/no spill; waves_per_eu(2,2)->128+
// spill; (256,4)->64+spill; (256,3)->84 slower. Stay at (256,2).
// ---------------------------------------------------------------------------

#define LDX(dst, g)                                                        \
    {                                                                      \
        const float* xr_ = xb + xrow0 * KCH + ((g) ^ xq) * 4;              \
        _Pragma("unroll")                                                  \
        for (int r_ = 0; r_ < 8; ++r_)                                     \
            dst[r_] = *(const float4*)(xr_ + r_ * 2 * KCH);                \
    }

#define LDWm(dst, g)                                                       \
    {                                                                      \
        const float* wr_ = wb + wrow0 * KCH + ((g) ^ wq) * 4;              \
        _Pragma("unroll")                                                  \
        for (int c_ = 0; c_ < 8; ++c_)                                     \
            dst[c_] = *(const float4*)(wr_ + c_ * 2 * KCH);                \
    }

#define FMA_COMP(xf, wf, COMP)                                             \
    _Pragma("unroll")                                                      \
    for (int r_ = 0; r_ < 8; ++r_)                                         \
        _Pragma("unroll")                                                  \
        for (int c_ = 0; c_ < 8; ++c_)                                     \
            acc[r_][c_] = __fmaf_rn(xf[r_].COMP, wf[c_].COMP, acc[r_][c_]);

#define FMA_GROUP(xf, wf)                                                  \
    FMA_COMP(xf, wf, x)                                                    \
    FMA_COMP(xf, wf, y)                                                    \
    FMA_COMP(xf, wf, z)                                                    \
    FMA_COMP(xf, wf, w)

// issue pattern for one group with 16 prefetch reads folded in:
// 8 x {2 DS_READ, 16 VALU} then 128 VALU tail (covers last read's latency)
#define SGB_INTERLEAVE                                                     \
    {                                                                      \
        _Pragma("unroll")                                                  \
        for (int i_ = 0; i_ < 8; ++i_) {                                   \
            __builtin_amdgcn_sched_group_barrier(0x100, 2, 0);  /*DS_READ*/\
            __builtin_amdgcn_sched_group_barrier(0x002, 16, 0); /*VALU*/   \
        }                                                                  \
        __builtin_amdgcn_sched_group_barrier(0x002, 128, 0);               \
    }

// plain group (no reads to fold): keep FMAs clustered
#define SGB_PLAIN                                                          \
    __builtin_amdgcn_sched_group_barrier(0x002, 256, 0);

__global__ __launch_bounds__(256, 2)
void snn_gemm_seqfma(const float* __restrict__ x, const float* __restrict__ W,
                     const float* __restrict__ bias, float* __restrict__ hidden) {
    __shared__ __align__(16) float xs[2 * TILEF];   // 16 KB
    __shared__ __align__(16) float ws[2 * TILEF];   // 16 KB

    const int tid = threadIdx.x;
    const int l   = tid & 63;
    const int wv  = __builtin_amdgcn_readfirstlane(tid >> 6);  // wave 0..3
    const int lx  = l & 7;           // h octet within wave sub-tile
    const int ly  = (l >> 3) & 7;    // bt octet within wave sub-tile
    const int bt0 = blockIdx.y * MBT;
    const int h0  = blockIdx.x * NBH;
    // wave sub-tile origin inside the 128x128 block tile
    const int wbt = 64 * (wv >> 1);  // bt offset: 0 or 64
    const int wh  = 64 * (wv & 1);   // h  offset: 0 or 64

    // ---- DMA staging: wave wv stages windows 2wv, 2wv+1 (16 rows each) ----
    const int rl = l >> 2;                        // slot within window, 0..15
    const int qs = l & 3;                         // quad position, 0..3
    const int g0 = ((rl & 1) << 3) | (rl >> 1);   // global row offset for slot
    const int wA = 2 * wv;
    const int wB = 2 * wv + 1;
    const int rA = wA * 16 + g0;
    const int rB = wB * 16 + g0;
    const int qA = qs ^ (wA & 3);
    const int qB = qs ^ (wB & 3);
    const float* xgA = x + (size_t)(bt0 + rA) * INF + qA * 4;
    const float* xgB = x + (size_t)(bt0 + rB) * INF + qB * 4;
    const float* wgA = W + (size_t)(h0 + rA) * INF + qA * 4;
    const float* wgB = W + (size_t)(h0 + rB) * INF + qB * 4;
    const int dOffA = (32 * wv) * KCH;        // wave-uniform LDS float offset
    const int dOffB = dOffA + 16 * KCH;

    // ---- prologue: stage chunk 0 into buffer 0 ----
    GLD16(xgA, xs + dOffA);
    GLD16(xgB, xs + dOffB);
    GLD16(wgA, ws + dOffA);
    GLD16(wgB, ws + dOffB);

    float acc[8][8];
    #pragma unroll
    for (int r = 0; r < 8; ++r)
        #pragma unroll
        for (int c = 0; c < 8; ++c) acc[r][c] = 0.0f;

    __syncthreads();   // drains vmcnt -> chunk 0 resident

    // per-lane read bases: octet o reads slots (o&1) + 2*idx of window (o>>1)
    const int xrow0 = wbt + (ly >> 1) * 16 + (ly & 1);
    const int wrow0 = wh  + (lx >> 1) * 16 + (lx & 1);
    const int xq = (ly >> 1) & 3;    // quad-XOR seen by this lane's x rows
    const int wq = (lx >> 1) & 3;    // quad-XOR seen by this lane's W rows

    for (int kc = 0; kc < NCH; ++kc) {
        const int p  = kc & 1;
        const int np = p ^ 1;

        // ---- issue next chunk's DMAs into the other buffer (async) ----
        if (kc + 1 < NCH) {
            const int so = (kc + 1) * KCH;    // float offset within a row
            float* xd = xs + np * TILEF;
            float* wd = ws + np * TILEF;
            GLD16(xgA + so, xd + dOffA);
            GLD16(xgB + so, xd + dOffB);
            GLD16(wgA + so, wd + dOffA);
            GLD16(wgB + so, wd + dOffB);
        }

        // ---- compute: 4 groups, g ascending; double-set rotation with
        //      SGB-pinned interleave (loads for g+1 under FMAs of g) ----
        const float* xb = xs + p * TILEF;
        const float* wb = ws + p * TILEF;
        float4 xfA[8], wfA[8], xfB[8], wfB[8];

        // group-0 operand loads issue first
        LDX(xfA, 0) LDWm(wfA, 0)
        __builtin_amdgcn_sched_group_barrier(0x100, 16, 0);   // 16 DS_READ

        // g = 0 (+ load g=1)
        LDX(xfB, 1) LDWm(wfB, 1)
        FMA_GROUP(xfA, wfA)
        SGB_INTERLEAVE

        // g = 1 (+ load g=2)
        LDX(xfA, 2) LDWm(wfA, 2)
        FMA_GROUP(xfB, wfB)
        SGB_INTERLEAVE

        // g = 2 (+ load g=3)
        LDX(xfB, 3) LDWm(wfB, 3)
        FMA_GROUP(xfA, wfA)
        SGB_INTERLEAVE

        // g = 3
        FMA_GROUP(xfB, wfB)
        SGB_PLAIN

        __syncthreads();   // all waves done with buf p; buf np's DMAs drained
    }

    // ---- epilogue: one fp32 rounding for bias, float4 stores ----
    float bv[8];
    #pragma unroll
    for (int c = 0; c < 8; ++c) bv[c] = bias[h0 + wh + lx * 8 + c];
    #pragma unroll
    for (int r = 0; r < 8; ++r) {
        float* orow = hidden + (size_t)(bt0 + wbt + ly * 8 + r) * HIDF
                             + h0 + wh + lx * 8;
        float4 o0, o1;
        o0.x = __fadd_rn(acc[r][0], bv[0]);
        o0.y = __fadd_rn(acc[r][1], bv[1]);
        o0.z = __fadd_rn(acc[r][2], bv[2]);
        o0.w = __fadd_rn(acc[r][3], bv[3]);
        o1.x = __fadd_rn(acc[r][4], bv[4]);
        o1.y = __fadd_rn(acc[r][5], bv[5]);
        o1.z = __fadd_rn(acc[r][6], bv[6]);
        o1.w = __fadd_rn(acc[r][7], bv[7]);
        ((float4*)orow)[0] = o0;
        ((float4*)orow)[1] = o1;
    }
}

// ---------------------------------------------------------------------------
// Phase 2: in-place LIF scan over t per (b,h) column, fp32:
//   mem = fl32(0.5*mem + h_t); spk = mem > 1.0f; hard reset to 0.
// Residual (total - gemm) is harness overhead + ~15-20 us scan; left as-is.
// ---------------------------------------------------------------------------
#define SEG 32

__global__ __launch_bounds__(64)
void snn_scan_np(float* __restrict__ io) {
    const int n = blockIdx.x * 64 + threadIdx.x;   // 0..32767
    const int b = n >> 10;
    const int h = n & 1023;
    float* p = io + (size_t)b * TIME * HIDF + h;

    float A[SEG], B[SEG];
    float mem = 0.0f;

    #pragma unroll
    for (int u = 0; u < SEG; ++u) A[u] = p[u * HIDF];

    for (int tb = 0; tb < TIME / SEG; tb += 2) {
        #pragma unroll
        for (int u = 0; u < SEG; ++u) B[u] = p[((tb + 1) * SEG + u) * HIDF];
        #pragma unroll
        for (int u = 0; u < SEG; ++u) {
            mem = __fadd_rn(__fmul_rn(0.5f, mem), A[u]);
            const bool s = mem > 1.0f;
            p[(tb * SEG + u) * HIDF] = s ? 1.0f : 0.0f;
            if (s) mem = 0.0f;
        }
        if (tb + 2 < TIME / SEG) {
            #pragma unroll
            for (int u = 0; u < SEG; ++u) A[u] = p[((tb + 2) * SEG + u) * HIDF];
        }
        #pragma unroll
        for (int u = 0; u < SEG; ++u) {
            mem = __fadd_rn(__fmul_rn(0.5f, mem), B[u]);
            const bool s = mem > 1.0f;
            p[((tb + 1) * SEG + u) * HIDF] = s ? 1.0f : 0.0f;
            if (s) mem = 0.0f;
        }
    }
}

extern "C" void kernel_launch(void* const* d_in, const int* in_sizes, int n_in,
                              void* d_out, int out_size, void* d_ws, size_t ws_size,
                              hipStream_t stream) {
    const float* x    = (const float*)d_in[0];   // [32, 512, 512]
    const float* W    = (const float*)d_in[1];   // [1024, 512]
    const float* bias = (const float*)d_in[2];   // [1024]
    float* out = (float*)d_out;                  // [32, 512, 1024]

    dim3 g1(HIDF / NBH, (BATCH * TIME) / MBT);   // (8, 128) = 1024 blocks
    snn_gemm_seqfma<<<g1, 256, 0, stream>>>(x, W, bias, out);

    snn_scan_np<<<(BATCH * HIDF) / 64, 64, 0, stream>>>(out);
}

// Round 10
// 317.275 us; speedup vs baseline: 2.1824x; 1.0313x over previous
//
#include <hip/hip_runtime.h>

#define BATCH 32
#define TIME  512
#define INF   512
#define HIDF  1024

#define MBT  128          // block tile: bt rows
#define NBH  128          // block tile: h cols
#define KCH  16           // k per chunk
#define NCH  (INF / KCH)  // 32 chunks
#define TILEF (MBT * KCH) // 2048 floats = 8 KB per buffer

// async global->LDS DMA, 16 B per lane, dst = wave-uniform base + lane*16
#define GLD16(g, l) __builtin_amdgcn_global_load_lds(                      \
    (const __attribute__((address_space(1))) void*)(g),                    \
    (__attribute__((address_space(3))) void*)(l), 16, 0, 0)

// ---------------------------------------------------------------------------
// Phase 1: hidden[bt][h] = (sum_k x[bt,k]*W[h,k]) + bias[h], bit-exact vs the
// XLA canonical order: ONE fp32 accumulator per output, fused FMA, k strictly
// ascending, ONE fp32 rounding for +bias.
//
// R17 = exact revert to R11 (proven best: 240.5 us, VGPR 88, 0 conflicts).
// Closed investigation (R8-R16): the LDS pipe is saturated at ~17.6 cyc per
// 8-address-broadcast ds_read_b128 (576k cyc / 32768 reads/CU = 240 us,
// matches measurement). Read count is at its floor: reads/FMA=(m+n)/4mn is
// minimal at the square 8x8 lane tile, and 8x8 is the largest tile under
// the toolchain's hard 128-VGPR ceiling (R9: launch_bounds(256,2)->clamp
// 128+spill at 8x16; R10: waves_per_eu(2,2)->same; R12: (256,4)->clamp 64
// +spill). Order (R16 SGB: null), sync (R13 barrier-free: null), occupancy
// (R14 3w: worse), operand placement (R15 W-from-global: 2.7x worse) all
// exhausted. ~240 us is the floor for bit-exact fp32 (no fp32 MFMA).
//
// Conflict-free LDS scheme (verified 0 conflicts): within each 16-row
// window, global row 8*(s&1)+(s>>1) is staged into slot s (pure GLOBAL-
// source permutation of GLD16; LDS dst linear), plus quad-XOR by (window&3).
// Octet ly reads slots (ly&1)+2r of window (ly>>1): bank group
// (ly&1)*16 + (g^(ly>>1))*4 -> 8 distinct quads, all 32 banks exactly once.
// The permutation composes so lane ly still gets exactly global rows
// wbt+8*ly+r with k-quads ascending: stores + FMA order unchanged.
// ---------------------------------------------------------------------------
__global__ __launch_bounds__(256, 2)
void snn_gemm_seqfma(const float* __restrict__ x, const float* __restrict__ W,
                     const float* __restrict__ bias, float* __restrict__ hidden) {
    __shared__ __align__(16) float xs[2 * TILEF];   // 16 KB
    __shared__ __align__(16) float ws[2 * TILEF];   // 16 KB

    const int tid = threadIdx.x;
    const int l   = tid & 63;
    const int wv  = __builtin_amdgcn_readfirstlane(tid >> 6);  // wave 0..3
    const int lx  = l & 7;           // h octet within wave sub-tile
    const int ly  = (l >> 3) & 7;    // bt octet within wave sub-tile
    const int bt0 = blockIdx.y * MBT;
    const int h0  = blockIdx.x * NBH;
    // wave sub-tile origin inside the 128x128 block tile
    const int wbt = 64 * (wv >> 1);  // bt offset: 0 or 64
    const int wh  = 64 * (wv & 1);   // h  offset: 0 or 64

    // ---- DMA staging: wave wv stages windows 2wv, 2wv+1 (16 rows each) ----
    // slot s in a window holds global row offset 8*(s&1) + (s>>1); quad
    // position q holds data quad q ^ (window&3).
    const int rl = l >> 2;                        // slot within window, 0..15
    const int qs = l & 3;                         // quad position, 0..3
    const int g0 = ((rl & 1) << 3) | (rl >> 1);   // global row offset for slot
    const int wA = 2 * wv;                        // window indices
    const int wB = 2 * wv + 1;
    const int rA = wA * 16 + g0;                  // global row (block-rel)
    const int rB = wB * 16 + g0;
    const int qA = qs ^ (wA & 3);
    const int qB = qs ^ (wB & 3);
    const float* xgA = x + (size_t)(bt0 + rA) * INF + qA * 4;
    const float* xgB = x + (size_t)(bt0 + rB) * INF + qB * 4;
    const float* wgA = W + (size_t)(h0 + rA) * INF + qA * 4;
    const float* wgB = W + (size_t)(h0 + rB) * INF + qB * 4;
    const int dOffA = (32 * wv) * KCH;        // wave-uniform LDS float offset
    const int dOffB = dOffA + 16 * KCH;

    // ---- prologue: stage chunk 0 into buffer 0 ----
    GLD16(xgA, xs + dOffA);
    GLD16(xgB, xs + dOffB);
    GLD16(wgA, ws + dOffA);
    GLD16(wgB, ws + dOffB);

    float acc[8][8];
    #pragma unroll
    for (int r = 0; r < 8; ++r)
        #pragma unroll
        for (int c = 0; c < 8; ++c) acc[r][c] = 0.0f;

    __syncthreads();   // drains vmcnt -> chunk 0 resident

    // per-lane read bases: octet o reads slots (o&1) + 2*idx of window (o>>1)
    const int xrow0 = wbt + (ly >> 1) * 16 + (ly & 1);
    const int wrow0 = wh  + (lx >> 1) * 16 + (lx & 1);
    const int xq = (ly >> 1) & 3;    // quad-XOR seen by this lane's x rows
    const int wq = (lx >> 1) & 3;    // quad-XOR seen by this lane's W rows

    for (int kc = 0; kc < NCH; ++kc) {
        const int p  = kc & 1;
        const int np = p ^ 1;

        // ---- issue next chunk's DMAs into the other buffer (async) ----
        if (kc + 1 < NCH) {
            const int so = (kc + 1) * KCH;    // float offset within a row
            float* xd = xs + np * TILEF;
            float* wd = ws + np * TILEF;
            GLD16(xgA + so, xd + dOffA);
            GLD16(xgB + so, xd + dOffB);
            GLD16(wgA + so, wd + dOffA);
            GLD16(wgB + so, wd + dOffB);
        }

        // ---- compute on current buffer: 4 groups of 4 k, g ascending ----
        const float* xb = xs + p * TILEF;
        const float* wb = ws + p * TILEF;
        #pragma unroll
        for (int g = 0; g < 4; ++g) {
            const int gx_ = (g ^ xq) * 4;     // storage quad for x rows
            const int gw_ = (g ^ wq) * 4;     // storage quad for W rows
            const float* xr = xb + xrow0 * KCH + gx_;
            const float* wr = wb + wrow0 * KCH + gw_;
            float4 xf[8], wf[8];
            #pragma unroll
            for (int r = 0; r < 8; ++r)
                xf[r] = *(const float4*)(xr + r * 2 * KCH);   // slot +2 rows
            #pragma unroll
            for (int c = 0; c < 8; ++c)
                wf[c] = *(const float4*)(wr + c * 2 * KCH);
            // xf[r] = data quads g of global row wbt+8ly+r (k ascending);
            // k strictly ascending within the group for every (r,c) chain
            #pragma unroll
            for (int r = 0; r < 8; ++r)
                #pragma unroll
                for (int c = 0; c < 8; ++c)
                    acc[r][c] = __fmaf_rn(xf[r].x, wf[c].x, acc[r][c]);
            #pragma unroll
            for (int r = 0; r < 8; ++r)
                #pragma unroll
                for (int c = 0; c < 8; ++c)
                    acc[r][c] = __fmaf_rn(xf[r].y, wf[c].y, acc[r][c]);
            #pragma unroll
            for (int r = 0; r < 8; ++r)
                #pragma unroll
                for (int c = 0; c < 8; ++c)
                    acc[r][c] = __fmaf_rn(xf[r].z, wf[c].z, acc[r][c]);
            #pragma unroll
            for (int r = 0; r < 8; ++r)
                #pragma unroll
                for (int c = 0; c < 8; ++c)
                    acc[r][c] = __fmaf_rn(xf[r].w, wf[c].w, acc[r][c]);
        }
        __syncthreads();   // all waves done with buf p; buf np's DMAs drained
    }

    // ---- epilogue: one fp32 rounding for bias, float4 stores ----
    float bv[8];
    #pragma unroll
    for (int c = 0; c < 8; ++c) bv[c] = bias[h0 + wh + lx * 8 + c];
    #pragma unroll
    for (int r = 0; r < 8; ++r) {
        float* orow = hidden + (size_t)(bt0 + wbt + ly * 8 + r) * HIDF
                             + h0 + wh + lx * 8;
        float4 o0, o1;
        o0.x = __fadd_rn(acc[r][0], bv[0]);
        o0.y = __fadd_rn(acc[r][1], bv[1]);
        o0.z = __fadd_rn(acc[r][2], bv[2]);
        o0.w = __fadd_rn(acc[r][3], bv[3]);
        o1.x = __fadd_rn(acc[r][4], bv[4]);
        o1.y = __fadd_rn(acc[r][5], bv[5]);
        o1.z = __fadd_rn(acc[r][6], bv[6]);
        o1.w = __fadd_rn(acc[r][7], bv[7]);
        ((float4*)orow)[0] = o0;
        ((float4*)orow)[1] = o1;
    }
}

// ---------------------------------------------------------------------------
// Phase 2: in-place LIF scan over t per (b,h) column, fp32:
//   mem = fl32(0.5*mem + h_t); spk = mem > 1.0f; hard reset to 0.
// R17: SEG 32->64 (halves exposed HBM round-trips 8->4 at the forced
// 2 waves/CU occupancy; 512 waves = one per column, sequential in t).
// Per-column math sequence unchanged -> bit-exact.
// ---------------------------------------------------------------------------
#define SEG 64

__global__ __launch_bounds__(64)
void snn_scan_np(float* __restrict__ io) {
    const int n = blockIdx.x * 64 + threadIdx.x;   // 0..32767
    const int b = n >> 10;
    const int h = n & 1023;
    float* p = io + (size_t)b * TIME * HIDF + h;

    float A[SEG], B[SEG];
    float mem = 0.0f;

    #pragma unroll
    for (int u = 0; u < SEG; ++u) A[u] = p[u * HIDF];

    for (int tb = 0; tb < TIME / SEG; tb += 2) {
        #pragma unroll
        for (int u = 0; u < SEG; ++u) B[u] = p[((tb + 1) * SEG + u) * HIDF];
        #pragma unroll
        for (int u = 0; u < SEG; ++u) {
            mem = __fadd_rn(__fmul_rn(0.5f, mem), A[u]);
            const bool s = mem > 1.0f;
            p[(tb * SEG + u) * HIDF] = s ? 1.0f : 0.0f;
            if (s) mem = 0.0f;
        }
        if (tb + 2 < TIME / SEG) {
            #pragma unroll
            for (int u = 0; u < SEG; ++u) A[u] = p[((tb + 2) * SEG + u) * HIDF];
        }
        #pragma unroll
        for (int u = 0; u < SEG; ++u) {
            mem = __fadd_rn(__fmul_rn(0.5f, mem), B[u]);
            const bool s = mem > 1.0f;
            p[((tb + 1) * SEG + u) * HIDF] = s ? 1.0f : 0.0f;
            if (s) mem = 0.0f;
        }
    }
}

extern "C" void kernel_launch(void* const* d_in, const int* in_sizes, int n_in,
                              void* d_out, int out_size, void* d_ws, size_t ws_size,
                              hipStream_t stream) {
    const float* x    = (const float*)d_in[0];   // [32, 512, 512]
    const float* W    = (const float*)d_in[1];   // [1024, 512]
    const float* bias = (const float*)d_in[2];   // [1024]
    float* out = (float*)d_out;                  // [32, 512, 1024]

    dim3 g1(HIDF / NBH, (BATCH * TIME) / MBT);   // (8, 128) = 1024 blocks
    snn_gemm_seqfma<<<g1, 256, 0, stream>>>(x, W, bias, out);

    snn_scan_np<<<(BATCH * HIDF) / 64, 64, 0, stream>>>(out);
}